// Round 12
// baseline (1908.846 us; speedup 1.0000x reference)
//
#include <hip/hip_runtime.h>
#include <hip/hip_bf16.h>
#include <math.h>

#define BB   4
#define NN   10000
#define NP   10112          // NN padded to multiple of 128
#define EE   160000
#define DD   128
#define OUTD 64
#define LL   4
#define NEGS 0.01f
#define MSTR 136            // s_mid/s_ho row stride (bf16 elems)
#define RSH  68             // k_edge s_red row stride (bf16), conflict-free
#define NTB  32             // nodes per k_edge block (CSR range)

typedef __attribute__((ext_vector_type(8))) short   short8;
typedef __attribute__((ext_vector_type(4))) float   floatx4;
typedef __attribute__((ext_vector_type(4))) uint    uintx4;

__device__ __forceinline__ float lrelu(float x) { return fmaxf(x, NEGS * x); }
__device__ __forceinline__ ushort f2bf(float x) {
    uint u = __builtin_bit_cast(uint, x);
    return (ushort)((u + 0x7FFFu + ((u >> 16) & 1u)) >> 16);
}
__device__ __forceinline__ float bf2f(ushort u) {
    uint v = ((uint)u) << 16;
    return __builtin_bit_cast(float, v);
}
__device__ __forceinline__ float bcf(uint u) { return __builtin_bit_cast(float, u); }

// ---- all weights -> MFMA B-fragment layout in ONE launch
__global__ void k_cvtw_all(const float* __restrict__ ew1, const float* __restrict__ ew2,
                           const float* __restrict__ nw1, const float* __restrict__ nw2,
                           ushort* __restrict__ wtopf, ushort* __restrict__ wmidf,
                           ushort* __restrict__ ew2f, ushort* __restrict__ nw1f,
                           ushort* __restrict__ nw2f) {
    int tid = blockIdx.x * 256 + threadIdx.x;
    const float* src; ushort* dst; int pitch, nks, loc;
    if (tid < 8192)       { src = ew1;                     dst = wtopf; pitch = 257; nks = 4; loc = tid; }
    else if (tid < 16384) { src = ew1 + (size_t)128 * DD;  dst = wmidf; pitch = 257; nks = 4; loc = tid - 8192; }
    else if (tid < 24576) { src = ew2;                     dst = ew2f;  pitch = 128; nks = 4; loc = tid - 16384; }
    else if (tid < 40960) { src = nw1;                     dst = nw1f;  pitch = 256; nks = 8; loc = tid - 24576; }
    else                  { src = nw2;                     dst = nw2f;  pitch = 128; nks = 4; loc = tid - 40960; }
    int lane = loc & 63;
    int nt   = (loc >> 6) & 7;
    int ks   = (loc >> 9) % nks;
    int l    = loc / (nks * 512);
    int quad = lane >> 4, l16 = lane & 15;
    int n = nt * 16 + l16;
    const float* s = src + (size_t)l * pitch * DD;
    ushort* d = dst + (size_t)loc * 8;
    #pragma unroll
    for (int j = 0; j < 8; ++j)
        d[j] = f2bf(s[(size_t)(ks * 32 + quad * 8 + j) * DD + n]);
}

__global__ void k_h0(const float* __restrict__ x, const float* __restrict__ w0,
                     const float* __restrict__ b0, ushort* __restrict__ hb) {
    int idx = blockIdx.x * 256 + threadIdx.x;
    if (idx >= BB * NP * DD) return;
    int d  = idx & (DD - 1);
    int bn = idx >> 7;
    int n  = bn % NP, b = bn / NP;
    float v = 0.0f;
    if (n < NN) {
        const float* p = x + ((size_t)b * NN + n) * 3;
        v = lrelu(b0[d] + p[0] * w0[d] + p[1] * w0[DD + d] + p[2] * w0[2 * DD + d]);
    }
    hb[idx] = f2bf(v);
}

__global__ void k_count(const int* __restrict__ col, float* __restrict__ cnt,
                        int* __restrict__ ecnt) {
    int e = blockIdx.x * blockDim.x + threadIdx.x;
    if (e < EE) {
        int c = col[e];
        atomicAdd(&cnt[c], 1.0f);
        atomicAdd(&ecnt[c], 1);
    }
}

__global__ __launch_bounds__(256) void k_scan(const int* __restrict__ ecnt,
                                              int* __restrict__ cursor) {
    __shared__ int s_sum[256];
    int t = threadIdx.x;
    int base = t * 40;
    int s = 0;
    for (int i = 0; i < 40; ++i) {
        int n = base + i;
        if (n < NN) s += ecnt[n];
    }
    s_sum[t] = s;
    __syncthreads();
    if (t == 0) {
        int a = 0;
        for (int i = 0; i < 256; ++i) { int v = s_sum[i]; s_sum[i] = a; a += v; }
    }
    __syncthreads();
    int a = s_sum[t];
    for (int i = 0; i < 40; ++i) {
        int n = base + i;
        if (n < NN) { cursor[n] = a; a += ecnt[n]; }
    }
}

__global__ void k_place(const int* __restrict__ row, const int* __restrict__ col,
                        int* __restrict__ cursor,
                        int* __restrict__ rowS, int* __restrict__ colS) {
    int e = blockIdx.x * blockDim.x + threadIdx.x;
    if (e >= EE) return;
    int c = col[e];
    int p = atomicAdd(&cursor[c], 1);
    rowS[p] = row[e];
    colS[p] = c;
}
// after k_place, cursor[n] == end offset of node n's edge span

// ---------------- initial P/Q (layer 0), 64-node blocks, XCD swizzle ----------------
__global__ __launch_bounds__(256) void k_pq(
    const ushort* __restrict__ hb, const ushort* __restrict__ wtf,
    const ushort* __restrict__ wmf, const float* __restrict__ b1,
    ushort* __restrict__ P, ushort* __restrict__ Q)
{
    __shared__ __align__(16) ushort s_out[64 * MSTR];
    const int g = blockIdx.x;
    const int b = (g >> 1) & 3;
    const int n0 = ((g >> 3) * 2 + (g & 1)) * 64;
    const int t = threadIdx.x;
    const int w = t >> 6, lane = t & 63, quad = lane >> 4, l16 = lane & 15;
    const int rw = w * 16;
    const int nw = n0 + rw;

    const ushort* hptr = hb + ((size_t)b * NP + nw + l16) * DD;
    float b1r[8];
    #pragma unroll
    for (int nt = 0; nt < 8; ++nt) b1r[nt] = b1[nt * 16 + l16];

    const short8* wt = (const short8*)wtf;
    const short8* wm = (const short8*)wmf;

    #pragma unroll
    for (int pass = 0; pass < 2; ++pass) {
        floatx4 ap[8];
        #pragma unroll
        for (int nt = 0; nt < 8; ++nt)
            #pragma unroll
            for (int r = 0; r < 4; ++r) ap[nt][r] = pass ? b1r[nt] : 0.0f;
        const short8* wv = pass ? wm : wt;
        #pragma unroll
        for (int ks = 0; ks < 4; ++ks) {
            short8 bf[8];
            #pragma unroll
            for (int nt = 0; nt < 8; ++nt) bf[nt] = wv[(ks * 8 + nt) * 64 + lane];
            short8 af = *(const short8*)(hptr + ks * 32 + quad * 8);
            #pragma unroll
            for (int nt = 0; nt < 8; ++nt)
                ap[nt] = __builtin_amdgcn_mfma_f32_16x16x32_bf16(af, bf[nt], ap[nt], 0, 0, 0);
        }
        #pragma unroll
        for (int nt = 0; nt < 8; ++nt)
            #pragma unroll
            for (int r = 0; r < 4; ++r)
                s_out[(rw + quad * 4 + r) * MSTR + nt * 16 + l16] = f2bf(ap[nt][r]);
        ushort* dst = pass ? Q : P;
        #pragma unroll
        for (int i = 0; i < 4; ++i) {
            int row = rw + i * 4 + quad;
            short8 v = *(const short8*)&s_out[row * MSTR + l16 * 8];
            *(short8*)(dst + ((size_t)b * NP + n0 + row) * DD + l16 * 8) = v;
        }
    }
}

// ---------------- edge kernel: CSR node-range blocks, LDS aggregation, no global atomics ----------------
// Block owns nodes [n0, n0+32); loops over its sorted edge span in 128-edge chunks.
__global__ __launch_bounds__(256, 4) void k_edge(
    const float* __restrict__ pos,
    const ushort* __restrict__ P, const ushort* __restrict__ Q,
    const int* __restrict__ rowS, const int* __restrict__ colS,
    const int* __restrict__ cursor,
    const float* __restrict__ w1last,
    const ushort* __restrict__ w2f, const float* __restrict__ b2,
    float* __restrict__ aggr)
{
    __shared__ int    s_row[128];
    __shared__ int    s_colL[128];                     // block-local col 0..31
    __shared__ float  s_ds[128];
    __shared__ __align__(16) ushort s_red[128 * RSH];  // 17.4 KB scan staging (bf16)
    __shared__ __align__(16) float  s_aggr[NTB * DD];  // 16 KB block accumulator

    const int g    = blockIdx.x;
    const int b    = (g >> 1) & 3;
    const int n0   = ((g >> 3) * 2 + (g & 1)) * NTB;
    const int t    = threadIdx.x;
    const int w    = t >> 6, lane = t & 63;
    const int quad = lane >> 4, l16 = lane & 15;
    const int ew   = w * 32;

    const int e_start = (n0 == 0) ? 0 : cursor[((n0 <= NN) ? n0 : NN) - 1];
    const int e_end   = cursor[(n0 + NTB - 1 < NN) ? (n0 + NTB - 1) : (NN - 1)];
    const int ec      = e_end - e_start;
    const int nch     = (ec + 127) >> 7;

    // zero block accumulator
    {
        floatx4* za = (floatx4*)s_aggr;
        #pragma unroll
        for (int i = 0; i < 4; ++i) za[t + i * 256] = (floatx4){0.f, 0.f, 0.f, 0.f};
    }

    float b2r[8];
    #pragma unroll
    for (int nt = 0; nt < 8; ++nt) b2r[nt] = b2[nt * 16 + l16];
    const short8* w2v = (const short8*)w2f;

    for (int c = 0; c < nch; ++c) {
        __syncthreads();   // aggr-zero / previous chunk's scan done before restage
        if (t < 128) {
            int be = c * 128 + t;
            int r = 0, cl = 0; float dsq = 0.0f;
            if (be < ec) {
                int e = e_start + be;
                r = rowS[e];
                int cc = colS[e];
                cl = cc - n0;
                const float* pr = pos + ((size_t)b * NN + r) * 3;
                const float* pc = pos + ((size_t)b * NN + cc) * 3;
                float dx = pr[0] - pc[0], dy = pr[1] - pc[1], dz = pr[2] - pc[2];
                dsq = dx * dx + dy * dy + dz * dz;
            }
            s_row[t] = r;
            s_colL[t] = cl;
            s_ds[t] = dsq;
        }
        __syncthreads();

        const ushort* pp[2];
        const ushort* qp[2];
        float dsv[2];
        #pragma unroll
        for (int mt = 0; mt < 2; ++mt) {
            int el = ew + mt * 16 + l16;
            pp[mt]  = P + ((size_t)b * NP + s_row[el]) * DD;
            qp[mt]  = Q + ((size_t)b * NP + n0 + s_colL[el]) * DD;
            dsv[mt] = s_ds[el];
        }

        uintx4 pf[2][4], qf[2][4];
        #pragma unroll
        for (int ks = 0; ks < 4; ++ks) {
            const int koff = ks * 32 + quad * 8;
            #pragma unroll
            for (int mt = 0; mt < 2; ++mt) {
                pf[mt][ks] = *(const uintx4*)(pp[mt] + koff);
                qf[mt][ks] = *(const uintx4*)(qp[mt] + koff);
            }
        }

        uintx4 mid[2][4];
        #pragma unroll
        for (int ks = 0; ks < 4; ++ks) {
            const int koff = ks * 32 + quad * 8;
            floatx4 wl0 = *(const floatx4*)(w1last + koff);
            floatx4 wl1 = *(const floatx4*)(w1last + koff + 4);
            float wl[8] = {wl0[0], wl0[1], wl0[2], wl0[3], wl1[0], wl1[1], wl1[2], wl1[3]};
            #pragma unroll
            for (int mt = 0; mt < 2; ++mt) {
                #pragma unroll
                for (int i = 0; i < 4; ++i) {
                    uint pv = pf[mt][ks][i], qv = qf[mt][ks][i];
                    float vlo = lrelu(bcf(pv << 16) + bcf(qv << 16) + dsv[mt] * wl[2 * i]);
                    float vhi = lrelu(bcf(pv & 0xFFFF0000u) + bcf(qv & 0xFFFF0000u) + dsv[mt] * wl[2 * i + 1]);
                    mid[mt][ks][i] = (__builtin_bit_cast(uint, vlo) >> 16) |
                                     (__builtin_bit_cast(uint, vhi) & 0xFFFF0000u);
                }
            }
        }

        const int lim = ec - c * 128 - ew;   // valid rows in this wave's window
        #pragma unroll
        for (int ph = 0; ph < 2; ++ph) {
            floatx4 acc[2][4];
            #pragma unroll
            for (int mt = 0; mt < 2; ++mt)
                #pragma unroll
                for (int ntl = 0; ntl < 4; ++ntl)
                    #pragma unroll
                    for (int r = 0; r < 4; ++r) acc[mt][ntl][r] = b2r[ph * 4 + ntl];

            #pragma unroll
            for (int ks = 0; ks < 4; ++ks) {
                short8 bf[4];
                #pragma unroll
                for (int ntl = 0; ntl < 4; ++ntl)
                    bf[ntl] = w2v[(ks * 8 + ph * 4 + ntl) * 64 + lane];
                #pragma unroll
                for (int mt = 0; mt < 2; ++mt) {
                    short8 af = __builtin_bit_cast(short8, mid[mt][ks]);
                    #pragma unroll
                    for (int ntl = 0; ntl < 4; ++ntl)
                        acc[mt][ntl] = __builtin_amdgcn_mfma_f32_16x16x32_bf16(af, bf[ntl], acc[mt][ntl], 0, 0, 0);
                }
            }

            // msg (bf16) to wave-private LDS rows, then segmented scan into s_aggr (ds_add)
            #pragma unroll
            for (int mt = 0; mt < 2; ++mt)
                #pragma unroll
                for (int ntl = 0; ntl < 4; ++ntl)
                    #pragma unroll
                    for (int r = 0; r < 4; ++r)
                        s_red[(ew + mt * 16 + quad * 4 + r) * RSH + ntl * 16 + l16] =
                            f2bf(lrelu(acc[mt][ntl][r]));

            const int d = ph * 64 + lane;
            float run = 0.0f;
            int prev = s_colL[ew];
            for (int r = 0; r < 32; ++r) {
                int cid = s_colL[ew + r];
                float v = (r < lim) ? bf2f(s_red[(ew + r) * RSH + lane]) : 0.0f;
                if (cid != prev) {
                    atomicAdd(&s_aggr[prev * DD + d], run);
                    run = 0.0f;
                    prev = cid;
                }
                run += v;
            }
            atomicAdd(&s_aggr[prev * DD + d], run);
        }
    }

    __syncthreads();
    // coalesced writeback: block owns aggr rows [n0, n0+32)
    {
        float* dst = aggr + ((size_t)b * NP + n0) * DD;
        const floatx4* sa = (const floatx4*)s_aggr;
        floatx4* da = (floatx4*)dst;
        #pragma unroll
        for (int i = 0; i < 4; ++i) da[t + i * 256] = sa[t + i * 256];
    }
}

// ---------------- node MLP: bf16-only h, LDS old-h staging, fused P/Q (no aggr clean) ----------------
__global__ __launch_bounds__(256) void k_node(
    ushort* hb, const float* __restrict__ aggr, const float* __restrict__ cnt,
    const float* __restrict__ cw, const float* __restrict__ cb,
    const ushort* __restrict__ w1f, const float* __restrict__ b1,
    const ushort* __restrict__ w2f, const float* __restrict__ b2,
    float* __restrict__ pos,
    int do_pq,
    const ushort* __restrict__ wtn, const ushort* __restrict__ wmn,
    const float* __restrict__ b1n,
    ushort* __restrict__ P, ushort* __restrict__ Q)
{
    __shared__ __align__(16) ushort s_mid[64 * MSTR];
    __shared__ __align__(16) ushort s_ho[64 * MSTR];

    const int g    = blockIdx.x;
    const int b    = (g >> 1) & 3;
    const int n0   = ((g >> 3) * 2 + (g & 1)) * 64;
    const int t    = threadIdx.x;
    const int w    = t >> 6, lane = t & 63;
    const int quad = lane >> 4, l16 = lane & 15;
    const int rw   = w * 16;
    const int nw   = n0 + rw;

    #pragma unroll
    for (int i = 0; i < 4; ++i) {
        int row = rw + i * 4 + quad;
        short8 v = *(const short8*)(hb + ((size_t)b * NP + n0 + row) * DD + l16 * 8);
        *(short8*)&s_ho[row * MSTR + l16 * 8] = v;
    }

    const float* aptr = aggr + ((size_t)b * NP + nw + l16) * DD;
    float inv = 0.0f;
    {
        int node = nw + l16;
        if (node < NN) { float dn = cnt[node]; inv = 1.0f / fmaxf(dn, 1.0f); }
    }
    float b1r[8], b2r[8];
    #pragma unroll
    for (int nt = 0; nt < 8; ++nt) {
        int d = nt * 16 + l16;
        b1r[nt] = b1[d]; b2r[nt] = b2[d];
    }

    floatx4 acc[8];
    #pragma unroll
    for (int nt = 0; nt < 8; ++nt)
        #pragma unroll
        for (int r = 0; r < 4; ++r) acc[nt][r] = b1r[nt];

    float cwacc = 0.0f;
    const short8* w1v = (const short8*)w1f;
    #pragma unroll
    for (int ks = 0; ks < 8; ++ks) {
        short8 bf[8];
        #pragma unroll
        for (int nt = 0; nt < 8; ++nt) bf[nt] = w1v[(ks * 8 + nt) * 64 + lane];
        const int koff = (ks & 3) * 32 + quad * 8;
        if (ks < 4) {
            short8 af = *(const short8*)(&s_ho[(rw + l16) * MSTR + koff]);
            #pragma unroll
            for (int nt = 0; nt < 8; ++nt)
                acc[nt] = __builtin_amdgcn_mfma_f32_16x16x32_bf16(af, bf[nt], acc[nt], 0, 0, 0);
        } else {
            floatx4 cw0 = *(const floatx4*)(cw + koff);
            floatx4 cw1 = *(const floatx4*)(cw + koff + 4);
            floatx4 a0 = *(const floatx4*)(aptr + koff);
            floatx4 a1 = *(const floatx4*)(aptr + koff + 4);
            short8 af;
            #pragma unroll
            for (int j = 0; j < 4; ++j) {
                float v = a0[j] * inv;
                af[j] = (short)f2bf(v);
                cwacc += v * cw0[j];
            }
            #pragma unroll
            for (int j = 0; j < 4; ++j) {
                float v = a1[j] * inv;
                af[4 + j] = (short)f2bf(v);
                cwacc += v * cw1[j];
            }
            #pragma unroll
            for (int nt = 0; nt < 8; ++nt)
                acc[nt] = __builtin_amdgcn_mfma_f32_16x16x32_bf16(af, bf[nt], acc[nt], 0, 0, 0);
        }
    }

    {
        float full = cwacc;
        full += __shfl_xor(full, 16);
        full += __shfl_xor(full, 32);
        int node = nw + l16;
        if (quad == 0 && node < NN) {
            float cu = 0.1f * tanhf(full + cb[0]);
            float* pp = pos + ((size_t)b * NN + node) * 3;
            pp[0] += cu; pp[1] += cu; pp[2] += cu;
        }
    }

    #pragma unroll
    for (int nt = 0; nt < 8; ++nt)
        #pragma unroll
        for (int r = 0; r < 4; ++r)
            s_mid[(rw + quad * 4 + r) * MSTR + nt * 16 + l16] = f2bf(lrelu(acc[nt][r]));

    floatx4 acc2[8];
    #pragma unroll
    for (int nt = 0; nt < 8; ++nt)
        #pragma unroll
        for (int r = 0; r < 4; ++r) acc2[nt][r] = b2r[nt];

    const short8* w2v = (const short8*)w2f;
    #pragma unroll
    for (int ks = 0; ks < 4; ++ks) {
        short8 bf[8];
        #pragma unroll
        for (int nt = 0; nt < 8; ++nt) bf[nt] = w2v[(ks * 8 + nt) * 64 + lane];
        short8 af = *(const short8*)(&s_mid[(rw + l16) * MSTR + ks * 32 + quad * 8]);
        #pragma unroll
        for (int nt = 0; nt < 8; ++nt)
            acc2[nt] = __builtin_amdgcn_mfma_f32_16x16x32_bf16(af, bf[nt], acc2[nt], 0, 0, 0);
    }

    #pragma unroll
    for (int nt = 0; nt < 8; ++nt)
        #pragma unroll
        for (int r = 0; r < 4; ++r) {
            int row = rw + quad * 4 + r;
            float hold = bf2f(s_ho[row * MSTR + nt * 16 + l16]);
            float hv = hold + lrelu(acc2[nt][r]);
            s_mid[row * MSTR + nt * 16 + l16] = f2bf(hv);
        }

    #pragma unroll
    for (int i = 0; i < 4; ++i) {
        int row = rw + i * 4 + quad;
        int n = n0 + row;
        short8 v = *(const short8*)&s_mid[row * MSTR + l16 * 8];
        if (n < NN)
            *(short8*)(hb + ((size_t)b * NP + n) * DD + l16 * 8) = v;
    }

    if (do_pq) {
        const short8* wt = (const short8*)wtn;
        const short8* wm = (const short8*)wmn;
        float b1nr[8];
        #pragma unroll
        for (int nt = 0; nt < 8; ++nt) b1nr[nt] = b1n[nt * 16 + l16];

        #pragma unroll
        for (int pass = 0; pass < 2; ++pass) {
            floatx4 ap[8];
            #pragma unroll
            for (int nt = 0; nt < 8; ++nt)
                #pragma unroll
                for (int r = 0; r < 4; ++r) ap[nt][r] = pass ? b1nr[nt] : 0.0f;
            const short8* wv = pass ? wm : wt;
            #pragma unroll
            for (int ks = 0; ks < 4; ++ks) {
                short8 bf[8];
                #pragma unroll
                for (int nt = 0; nt < 8; ++nt) bf[nt] = wv[(ks * 8 + nt) * 64 + lane];
                short8 af = *(const short8*)(&s_mid[(rw + l16) * MSTR + ks * 32 + quad * 8]);
                #pragma unroll
                for (int nt = 0; nt < 8; ++nt)
                    ap[nt] = __builtin_amdgcn_mfma_f32_16x16x32_bf16(af, bf[nt], ap[nt], 0, 0, 0);
            }
            #pragma unroll
            for (int nt = 0; nt < 8; ++nt)
                #pragma unroll
                for (int r = 0; r < 4; ++r)
                    s_ho[(rw + quad * 4 + r) * MSTR + nt * 16 + l16] = f2bf(ap[nt][r]);
            ushort* dst = pass ? Q : P;
            #pragma unroll
            for (int i = 0; i < 4; ++i) {
                int row = rw + i * 4 + quad;
                short8 v = *(const short8*)&s_ho[row * MSTR + l16 * 8];
                *(short8*)(dst + ((size_t)b * NP + n0 + row) * DD + l16 * 8) = v;
            }
        }
    }
}

#define NPC 50
__global__ void k_mean(const ushort* __restrict__ hb, float* __restrict__ hm) {
    int b  = blockIdx.y;
    int n0 = blockIdx.x * NPC;
    int d  = threadIdx.x;
    float s = 0.0f;
    for (int n = n0; n < n0 + NPC; ++n) s += bf2f(hb[((size_t)b * NP + n) * DD + d]);
    atomicAdd(&hm[b * DD + d], s);
}

__global__ void k_proj(const float* __restrict__ hm, const float* __restrict__ wp,
                       const float* __restrict__ bp, float* __restrict__ out) {
    int t = threadIdx.x;
    int b = t >> 6, o = t & (OUTD - 1);
    float s = 0.0f;
    for (int d2 = 0; d2 < DD; ++d2) s += hm[b * DD + d2] * wp[d2 * OUTD + o];
    s = s * (1.0f / NN) + bp[o];
    out[b * OUTD + o] = lrelu(s);
}

extern "C" void kernel_launch(void* const* d_in, const int* in_sizes, int n_in,
                              void* d_out, int out_size, void* d_ws, size_t ws_size,
                              hipStream_t stream) {
    (void)in_sizes; (void)n_in; (void)out_size; (void)ws_size;
    const float* x   = (const float*)d_in[0];
    const int*   ei  = (const int*)d_in[1];
    const float* w0  = (const float*)d_in[2];
    const float* b0  = (const float*)d_in[3];
    const float* ew1 = (const float*)d_in[4];
    const float* eb1 = (const float*)d_in[5];
    const float* ew2 = (const float*)d_in[6];
    const float* eb2 = (const float*)d_in[7];
    const float* cw  = (const float*)d_in[8];
    const float* cb  = (const float*)d_in[9];
    const float* nw1 = (const float*)d_in[10];
    const float* nb1 = (const float*)d_in[11];
    const float* nw2 = (const float*)d_in[12];
    const float* nb2 = (const float*)d_in[13];
    const float* wp  = (const float*)d_in[14];
    const float* bp  = (const float*)d_in[15];
    const int* row = ei;
    const int* col = ei + EE;

    const size_t HSZ = (size_t)BB * NP * DD;
    float* ws   = (float*)d_ws;
    float* aggr = ws;
    float* pos  = aggr + HSZ;
    float* cnt  = pos + (size_t)BB * NN * 3;
    float* hm   = cnt + NN;
    ushort* hb    = (ushort*)(hm + 512);
    ushort* Pb    = hb + HSZ;
    ushort* Qb    = Pb + HSZ;
    ushort* wtopf = Qb + HSZ;
    ushort* wmidf = wtopf + (size_t)LL * 16384;
    ushort* ew2f  = wmidf + (size_t)LL * 16384;
    ushort* nw1f  = ew2f + (size_t)LL * 16384;
    ushort* nw2f  = nw1f + (size_t)LL * 32768;
    int* ecnt   = (int*)(nw2f + (size_t)LL * 16384);
    int* cursor = ecnt + NN;
    int* rowS   = cursor + NN;
    int* colS   = rowS + EE;

    hipMemcpyAsync(pos, x, sizeof(float) * (size_t)BB * NN * 3,
                   hipMemcpyDeviceToDevice, stream);
    hipMemsetAsync(cnt, 0, sizeof(float) * NN, stream);
    hipMemsetAsync(ecnt, 0, sizeof(int) * NN, stream);
    hipMemsetAsync(hm, 0, sizeof(float) * BB * DD, stream);

    k_cvtw_all<<<192, 256, 0, stream>>>(ew1, ew2, nw1, nw2,
                                        wtopf, wmidf, ew2f, nw1f, nw2f);

    k_h0<<<((int)HSZ + 255) / 256, 256, 0, stream>>>(x, w0, b0, hb);
    k_count<<<(EE + 255) / 256, 256, 0, stream>>>(col, cnt, ecnt);
    k_scan<<<1, 256, 0, stream>>>(ecnt, cursor);
    k_place<<<(EE + 255) / 256, 256, 0, stream>>>(row, col, cursor, rowS, colS);

    k_pq<<<(NP / 64) * BB, 256, 0, stream>>>(hb, wtopf, wmidf, eb1, Pb, Qb);

    for (int i = 0; i < LL; ++i) {
        k_edge<<<(NP / NTB) * BB, 256, 0, stream>>>(
            pos, Pb, Qb, rowS, colS, cursor,
            ew1 + (size_t)i * 257 * DD + (size_t)256 * DD,
            ew2f + (size_t)i * 16384,
            eb2 + (size_t)i * DD,
            aggr);
        int nx = (i < LL - 1) ? (i + 1) : i;
        k_node<<<(NP / 64) * BB, 256, 0, stream>>>(
            hb, aggr, cnt,
            cw + (size_t)i * DD, cb + i,
            nw1f + (size_t)i * 32768, nb1 + (size_t)i * DD,
            nw2f + (size_t)i * 16384, nb2 + (size_t)i * DD,
            pos,
            (i < LL - 1) ? 1 : 0,
            wtopf + (size_t)nx * 16384, wmidf + (size_t)nx * 16384,
            eb1 + (size_t)nx * DD,
            Pb, Qb);
    }

    k_mean<<<dim3(NN / NPC, BB), DD, 0, stream>>>(hb, hm);
    k_proj<<<1, 256, 0, stream>>>(hm, wp, bp, (float*)d_out);
}

// Round 13
// 590.685 us; speedup vs baseline: 3.2316x; 3.2316x over previous
//
#include <hip/hip_runtime.h>
#include <hip/hip_bf16.h>
#include <math.h>

#define BB   4
#define NN   10000
#define NP   10112          // NN padded to multiple of 128
#define EE   160000         // = 1250 * 128
#define DD   128
#define OUTD 64
#define LL   4
#define NEGS 0.01f
#define MSTR 136            // s_mid/s_ho row stride (bf16 elems), 272B/row
#define RSF  68             // k_edge s_red row stride (fp32): (4*row+c)%32 -> 2-way max (free)

typedef __attribute__((ext_vector_type(8))) short   short8;
typedef __attribute__((ext_vector_type(4))) float   floatx4;
typedef __attribute__((ext_vector_type(4))) uint    uintx4;

__device__ __forceinline__ float lrelu(float x) { return fmaxf(x, NEGS * x); }
// fast RNE f32->bf16 (finite inputs only)
__device__ __forceinline__ ushort f2bf(float x) {
    uint u = __builtin_bit_cast(uint, x);
    return (ushort)((u + 0x7FFFu + ((u >> 16) & 1u)) >> 16);
}
__device__ __forceinline__ float bf2f(ushort u) {
    uint v = ((uint)u) << 16;
    return __builtin_bit_cast(float, v);
}
__device__ __forceinline__ float bcf(uint u) { return __builtin_bit_cast(float, u); }

// ---- all weights -> MFMA B-fragment layout in ONE launch (192 blocks x 256)
__global__ void k_cvtw_all(const float* __restrict__ ew1, const float* __restrict__ ew2,
                           const float* __restrict__ nw1, const float* __restrict__ nw2,
                           ushort* __restrict__ wtopf, ushort* __restrict__ wmidf,
                           ushort* __restrict__ ew2f, ushort* __restrict__ nw1f,
                           ushort* __restrict__ nw2f) {
    int tid = blockIdx.x * 256 + threadIdx.x;
    const float* src; ushort* dst; int pitch, nks, loc;
    if (tid < 8192)       { src = ew1;                     dst = wtopf; pitch = 257; nks = 4; loc = tid; }
    else if (tid < 16384) { src = ew1 + (size_t)128 * DD;  dst = wmidf; pitch = 257; nks = 4; loc = tid - 8192; }
    else if (tid < 24576) { src = ew2;                     dst = ew2f;  pitch = 128; nks = 4; loc = tid - 16384; }
    else if (tid < 40960) { src = nw1;                     dst = nw1f;  pitch = 256; nks = 8; loc = tid - 24576; }
    else                  { src = nw2;                     dst = nw2f;  pitch = 128; nks = 4; loc = tid - 40960; }
    int lane = loc & 63;
    int nt   = (loc >> 6) & 7;
    int ks   = (loc >> 9) % nks;
    int l    = loc / (nks * 512);
    int quad = lane >> 4, l16 = lane & 15;
    int n = nt * 16 + l16;
    const float* s = src + (size_t)l * pitch * DD;
    ushort* d = dst + (size_t)loc * 8;
    #pragma unroll
    for (int j = 0; j < 8; ++j)
        d[j] = f2bf(s[(size_t)(ks * 32 + quad * 8 + j) * DD + n]);
}

// h0: bf16 only (no fp32 master)
__global__ void k_h0(const float* __restrict__ x, const float* __restrict__ w0,
                     const float* __restrict__ b0, ushort* __restrict__ hb) {
    int idx = blockIdx.x * 256 + threadIdx.x;
    if (idx >= BB * NP * DD) return;
    int d  = idx & (DD - 1);
    int bn = idx >> 7;
    int n  = bn % NP, b = bn / NP;
    float v = 0.0f;
    if (n < NN) {
        const float* p = x + ((size_t)b * NN + n) * 3;
        v = lrelu(b0[d] + p[0] * w0[d] + p[1] * w0[DD + d] + p[2] * w0[2 * DD + d]);
    }
    hb[idx] = f2bf(v);
}

__global__ void k_count(const int* __restrict__ col, float* __restrict__ cnt,
                        int* __restrict__ ecnt) {
    int e = blockIdx.x * blockDim.x + threadIdx.x;
    if (e < EE) {
        int c = col[e];
        atomicAdd(&cnt[c], 1.0f);
        atomicAdd(&ecnt[c], 1);
    }
}

__global__ __launch_bounds__(256) void k_scan(const int* __restrict__ ecnt,
                                              int* __restrict__ cursor) {
    __shared__ int s_sum[256];
    int t = threadIdx.x;
    int base = t * 40;
    int s = 0;
    for (int i = 0; i < 40; ++i) {
        int n = base + i;
        if (n < NN) s += ecnt[n];
    }
    s_sum[t] = s;
    __syncthreads();
    if (t == 0) {
        int a = 0;
        for (int i = 0; i < 256; ++i) { int v = s_sum[i]; s_sum[i] = a; a += v; }
    }
    __syncthreads();
    int a = s_sum[t];
    for (int i = 0; i < 40; ++i) {
        int n = base + i;
        if (n < NN) { cursor[n] = a; a += ecnt[n]; }
    }
}

__global__ void k_place(const int* __restrict__ row, const int* __restrict__ col,
                        int* __restrict__ cursor,
                        int* __restrict__ rowS, int* __restrict__ colS) {
    int e = blockIdx.x * blockDim.x + threadIdx.x;
    if (e >= EE) return;
    int c = col[e];
    int p = atomicAdd(&cursor[c], 1);
    rowS[p] = row[e];
    colS[p] = c;
}

// ---------------- initial P/Q (layer 0), 64-node blocks, XCD swizzle ----------------
__global__ __launch_bounds__(256) void k_pq(
    const ushort* __restrict__ hb, const ushort* __restrict__ wtf,
    const ushort* __restrict__ wmf, const float* __restrict__ b1,
    ushort* __restrict__ P, ushort* __restrict__ Q)
{
    __shared__ __align__(16) ushort s_out[64 * MSTR];
    const int g = blockIdx.x;
    const int b = (g >> 1) & 3;
    const int n0 = ((g >> 3) * 2 + (g & 1)) * 64;
    const int t = threadIdx.x;
    const int w = t >> 6, lane = t & 63, quad = lane >> 4, l16 = lane & 15;
    const int rw = w * 16;
    const int nw = n0 + rw;

    const ushort* hptr = hb + ((size_t)b * NP + nw + l16) * DD;
    float b1r[8];
    #pragma unroll
    for (int nt = 0; nt < 8; ++nt) b1r[nt] = b1[nt * 16 + l16];

    const short8* wt = (const short8*)wtf;
    const short8* wm = (const short8*)wmf;

    #pragma unroll
    for (int pass = 0; pass < 2; ++pass) {
        floatx4 ap[8];
        #pragma unroll
        for (int nt = 0; nt < 8; ++nt)
            #pragma unroll
            for (int r = 0; r < 4; ++r) ap[nt][r] = pass ? b1r[nt] : 0.0f;
        const short8* wv = pass ? wm : wt;
        #pragma unroll
        for (int ks = 0; ks < 4; ++ks) {
            short8 bf[8];
            #pragma unroll
            for (int nt = 0; nt < 8; ++nt) bf[nt] = wv[(ks * 8 + nt) * 64 + lane];
            short8 af = *(const short8*)(hptr + ks * 32 + quad * 8);
            #pragma unroll
            for (int nt = 0; nt < 8; ++nt)
                ap[nt] = __builtin_amdgcn_mfma_f32_16x16x32_bf16(af, bf[nt], ap[nt], 0, 0, 0);
        }
        #pragma unroll
        for (int nt = 0; nt < 8; ++nt)
            #pragma unroll
            for (int r = 0; r < 4; ++r)
                s_out[(rw + quad * 4 + r) * MSTR + nt * 16 + l16] = f2bf(ap[nt][r]);
        ushort* dst = pass ? Q : P;
        #pragma unroll
        for (int i = 0; i < 4; ++i) {
            int row = rw + i * 4 + quad;
            short8 v = *(const short8*)&s_out[row * MSTR + l16 * 8];
            *(short8*)(dst + ((size_t)b * NP + n0 + row) * DD + l16 * 8) = v;
        }
    }
}

// ---------------- edge kernel: packed-dword mid, 2-phase GEMM2, fp32 seg-reduce ----------------
__global__ __launch_bounds__(256, 4) void k_edge(
    const float* __restrict__ pos,
    const ushort* __restrict__ P, const ushort* __restrict__ Q,
    const int* __restrict__ rowS, const int* __restrict__ colS,
    const float* __restrict__ w1last,
    const ushort* __restrict__ w2f, const float* __restrict__ b2,
    float* __restrict__ aggr)
{
    __shared__ int    s_row[128];
    __shared__ int    s_col[128];
    __shared__ float  s_ds[128];
    __shared__ float  s_red[128 * RSF];   // 34.8 KB fp32

    const int g    = blockIdx.x;
    const int b    = (g >> 1) & 3;
    const int tile = (g >> 3) * 2 + (g & 1);
    const int e0   = tile * 128;
    const int t    = threadIdx.x;
    const int w    = t >> 6, lane = t & 63;
    const int quad = lane >> 4, l16 = lane & 15;

    if (t < 128) {
        int e = e0 + t;
        int r = rowS[e], c = colS[e];
        s_row[t] = r;
        s_col[t] = c;
        const float* pr = pos + ((size_t)b * NN + r) * 3;
        const float* pc = pos + ((size_t)b * NN + c) * 3;
        float dx = pr[0] - pc[0], dy = pr[1] - pc[1], dz = pr[2] - pc[2];
        s_ds[t] = dx * dx + dy * dy + dz * dz;
    }
    __syncthreads();

    const int ew = w * 32;
    const ushort* pp[2];
    const ushort* qp[2];
    float dsv[2];
    #pragma unroll
    for (int mt = 0; mt < 2; ++mt) {
        int el = ew + mt * 16 + l16;
        pp[mt]  = P + ((size_t)b * NP + s_row[el]) * DD;
        qp[mt]  = Q + ((size_t)b * NP + s_col[el]) * DD;
        dsv[mt] = s_ds[el];
    }

    // issue ALL gathers up front (single overlappable stall)
    uintx4 pf[2][4], qf[2][4];
    #pragma unroll
    for (int ks = 0; ks < 4; ++ks) {
        const int koff = ks * 32 + quad * 8;
        #pragma unroll
        for (int mt = 0; mt < 2; ++mt) {
            pf[mt][ks] = *(const uintx4*)(pp[mt] + koff);
            qf[mt][ks] = *(const uintx4*)(qp[mt] + koff);
        }
    }

    // mid = lrelu(P+Q+ds*w1last): packed-dword extract (1 op each), trunc repack (3 ops/pair)
    uintx4 mid[2][4];
    #pragma unroll
    for (int ks = 0; ks < 4; ++ks) {
        const int koff = ks * 32 + quad * 8;
        floatx4 wl0 = *(const floatx4*)(w1last + koff);
        floatx4 wl1 = *(const floatx4*)(w1last + koff + 4);
        float wl[8] = {wl0[0], wl0[1], wl0[2], wl0[3], wl1[0], wl1[1], wl1[2], wl1[3]};
        #pragma unroll
        for (int mt = 0; mt < 2; ++mt) {
            #pragma unroll
            for (int i = 0; i < 4; ++i) {
                uint pv = pf[mt][ks][i], qv = qf[mt][ks][i];
                float vlo = lrelu(bcf(pv << 16) + bcf(qv << 16) + dsv[mt] * wl[2 * i]);
                float vhi = lrelu(bcf(pv & 0xFFFF0000u) + bcf(qv & 0xFFFF0000u) + dsv[mt] * wl[2 * i + 1]);
                mid[mt][ks][i] = (__builtin_bit_cast(uint, vlo) >> 16) |
                                 (__builtin_bit_cast(uint, vhi) & 0xFFFF0000u);
            }
        }
    }

    float b2r[8];
    #pragma unroll
    for (int nt = 0; nt < 8; ++nt) b2r[nt] = b2[nt * 16 + l16];

    const short8* w2v = (const short8*)w2f;
    #pragma unroll
    for (int ph = 0; ph < 2; ++ph) {
        floatx4 acc[2][4];
        #pragma unroll
        for (int mt = 0; mt < 2; ++mt)
            #pragma unroll
            for (int ntl = 0; ntl < 4; ++ntl)
                #pragma unroll
                for (int r = 0; r < 4; ++r) acc[mt][ntl][r] = b2r[ph * 4 + ntl];

        #pragma unroll
        for (int ks = 0; ks < 4; ++ks) {
            short8 bf[4];
            #pragma unroll
            for (int ntl = 0; ntl < 4; ++ntl)
                bf[ntl] = w2v[(ks * 8 + ph * 4 + ntl) * 64 + lane];
            #pragma unroll
            for (int mt = 0; mt < 2; ++mt) {
                short8 af = __builtin_bit_cast(short8, mid[mt][ks]);
                #pragma unroll
                for (int ntl = 0; ntl < 4; ++ntl)
                    acc[mt][ntl] = __builtin_amdgcn_mfma_f32_16x16x32_bf16(af, bf[ntl], acc[mt][ntl], 0, 0, 0);
            }
        }

        // msg straight to fp32 LDS (no conversion), wave-private rows; then segmented scan
        #pragma unroll
        for (int mt = 0; mt < 2; ++mt)
            #pragma unroll
            for (int ntl = 0; ntl < 4; ++ntl)
                #pragma unroll
                for (int r = 0; r < 4; ++r)
                    s_red[(ew + mt * 16 + quad * 4 + r) * RSF + ntl * 16 + l16] =
                        lrelu(acc[mt][ntl][r]);

        const int d = ph * 64 + lane;
        float run = 0.0f;
        int prev = s_col[ew];
        for (int r = 0; r < 32; ++r) {
            int cid = s_col[ew + r];
            float v = s_red[(ew + r) * RSF + lane];
            if (cid != prev) {
                atomicAdd(&aggr[((size_t)b * NP + prev) * DD + d], run);
                run = 0.0f;
                prev = cid;
            }
            run += v;
        }
        atomicAdd(&aggr[((size_t)b * NP + prev) * DD + d], run);
    }
}

// ---------------- node MLP: bf16-only h, LDS old-h staging, fused P/Q ----------------
__global__ __launch_bounds__(256) void k_node(
    ushort* hb, float* aggr, const float* __restrict__ cnt,
    const float* __restrict__ cw, const float* __restrict__ cb,
    const ushort* __restrict__ w1f, const float* __restrict__ b1,
    const ushort* __restrict__ w2f, const float* __restrict__ b2,
    float* __restrict__ pos,
    int do_pq,
    const ushort* __restrict__ wtn, const ushort* __restrict__ wmn,
    const float* __restrict__ b1n,
    ushort* __restrict__ P, ushort* __restrict__ Q)
{
    __shared__ __align__(16) ushort s_mid[64 * MSTR];
    __shared__ __align__(16) ushort s_ho[64 * MSTR];   // old-h; reused as PQ staging

    const int g    = blockIdx.x;
    const int b    = (g >> 1) & 3;
    const int n0   = ((g >> 3) * 2 + (g & 1)) * 64;
    const int t    = threadIdx.x;
    const int w    = t >> 6, lane = t & 63;
    const int quad = lane >> 4, l16 = lane & 15;
    const int rw   = w * 16;
    const int nw   = n0 + rw;

    // stage old h (coalesced b128, wave-private rows)
    #pragma unroll
    for (int i = 0; i < 4; ++i) {
        int row = rw + i * 4 + quad;
        short8 v = *(const short8*)(hb + ((size_t)b * NP + n0 + row) * DD + l16 * 8);
        *(short8*)&s_ho[row * MSTR + l16 * 8] = v;
    }

    float* aptr = aggr + ((size_t)b * NP + nw + l16) * DD;
    float inv = 0.0f;
    {
        int node = nw + l16;
        if (node < NN) { float dn = cnt[node]; inv = 1.0f / fmaxf(dn, 1.0f); }
    }
    float b1r[8], b2r[8];
    #pragma unroll
    for (int nt = 0; nt < 8; ++nt) {
        int d = nt * 16 + l16;
        b1r[nt] = b1[d]; b2r[nt] = b2[d];
    }

    floatx4 acc[8];
    #pragma unroll
    for (int nt = 0; nt < 8; ++nt)
        #pragma unroll
        for (int r = 0; r < 4; ++r) acc[nt][r] = b1r[nt];

    float cwacc = 0.0f;
    const floatx4 zero4 = {0.0f, 0.0f, 0.0f, 0.0f};
    const short8* w1v = (const short8*)w1f;
    #pragma unroll
    for (int ks = 0; ks < 8; ++ks) {
        short8 bf[8];
        #pragma unroll
        for (int nt = 0; nt < 8; ++nt) bf[nt] = w1v[(ks * 8 + nt) * 64 + lane];
        const int koff = (ks & 3) * 32 + quad * 8;
        if (ks < 4) {
            short8 af = *(const short8*)(&s_ho[(rw + l16) * MSTR + koff]);
            #pragma unroll
            for (int nt = 0; nt < 8; ++nt)
                acc[nt] = __builtin_amdgcn_mfma_f32_16x16x32_bf16(af, bf[nt], acc[nt], 0, 0, 0);
        } else {
            floatx4 cw0 = *(const floatx4*)(cw + koff);
            floatx4 cw1 = *(const floatx4*)(cw + koff + 4);
            floatx4 a0 = *(const floatx4*)(aptr + koff);
            floatx4 a1 = *(const floatx4*)(aptr + koff + 4);
            *(floatx4*)(aptr + koff)     = zero4;   // self-clean for next layer
            *(floatx4*)(aptr + koff + 4) = zero4;
            short8 af;
            #pragma unroll
            for (int j = 0; j < 4; ++j) {
                float v = a0[j] * inv;
                af[j] = (short)f2bf(v);
                cwacc += v * cw0[j];
            }
            #pragma unroll
            for (int j = 0; j < 4; ++j) {
                float v = a1[j] * inv;
                af[4 + j] = (short)f2bf(v);
                cwacc += v * cw1[j];
            }
            #pragma unroll
            for (int nt = 0; nt < 8; ++nt)
                acc[nt] = __builtin_amdgcn_mfma_f32_16x16x32_bf16(af, bf[nt], acc[nt], 0, 0, 0);
        }
    }

    // coord update
    {
        float full = cwacc;
        full += __shfl_xor(full, 16);
        full += __shfl_xor(full, 32);
        int node = nw + l16;
        if (quad == 0 && node < NN) {
            float cu = 0.1f * tanhf(full + cb[0]);
            float* pp = pos + ((size_t)b * NN + node) * 3;
            pp[0] += cu; pp[1] += cu; pp[2] += cu;
        }
    }

    #pragma unroll
    for (int nt = 0; nt < 8; ++nt)
        #pragma unroll
        for (int r = 0; r < 4; ++r)
            s_mid[(rw + quad * 4 + r) * MSTR + nt * 16 + l16] = f2bf(lrelu(acc[nt][r]));

    floatx4 acc2[8];
    #pragma unroll
    for (int nt = 0; nt < 8; ++nt)
        #pragma unroll
        for (int r = 0; r < 4; ++r) acc2[nt][r] = b2r[nt];

    const short8* w2v = (const short8*)w2f;
    #pragma unroll
    for (int ks = 0; ks < 4; ++ks) {
        short8 bf[8];
        #pragma unroll
        for (int nt = 0; nt < 8; ++nt) bf[nt] = w2v[(ks * 8 + nt) * 64 + lane];
        short8 af = *(const short8*)(&s_mid[(rw + l16) * MSTR + ks * 32 + quad * 8]);
        #pragma unroll
        for (int nt = 0; nt < 8; ++nt)
            acc2[nt] = __builtin_amdgcn_mfma_f32_16x16x32_bf16(af, bf[nt], acc2[nt], 0, 0, 0);
    }

    // residual from s_ho (bf16 old h), new h -> s_mid
    #pragma unroll
    for (int nt = 0; nt < 8; ++nt)
        #pragma unroll
        for (int r = 0; r < 4; ++r) {
            int row = rw + quad * 4 + r;
            float hold = bf2f(s_ho[row * MSTR + nt * 16 + l16]);
            float hv = hold + lrelu(acc2[nt][r]);
            s_mid[row * MSTR + nt * 16 + l16] = f2bf(hv);
        }

    // hb write-back, vectorized from s_mid (wave-private rows)
    #pragma unroll
    for (int i = 0; i < 4; ++i) {
        int row = rw + i * 4 + quad;
        int n = n0 + row;
        short8 v = *(const short8*)&s_mid[row * MSTR + l16 * 8];
        if (n < NN)
            *(short8*)(hb + ((size_t)b * NP + n) * DD + l16 * 8) = v;
    }

    // fused next-layer P/Q from s_mid (new h), staged via s_ho (old h dead now)
    if (do_pq) {
        const short8* wt = (const short8*)wtn;
        const short8* wm = (const short8*)wmn;
        float b1nr[8];
        #pragma unroll
        for (int nt = 0; nt < 8; ++nt) b1nr[nt] = b1n[nt * 16 + l16];

        #pragma unroll
        for (int pass = 0; pass < 2; ++pass) {
            floatx4 ap[8];
            #pragma unroll
            for (int nt = 0; nt < 8; ++nt)
                #pragma unroll
                for (int r = 0; r < 4; ++r) ap[nt][r] = pass ? b1nr[nt] : 0.0f;
            const short8* wv = pass ? wm : wt;
            #pragma unroll
            for (int ks = 0; ks < 4; ++ks) {
                short8 bf[8];
                #pragma unroll
                for (int nt = 0; nt < 8; ++nt) bf[nt] = wv[(ks * 8 + nt) * 64 + lane];
                short8 af = *(const short8*)(&s_mid[(rw + l16) * MSTR + ks * 32 + quad * 8]);
                #pragma unroll
                for (int nt = 0; nt < 8; ++nt)
                    ap[nt] = __builtin_amdgcn_mfma_f32_16x16x32_bf16(af, bf[nt], ap[nt], 0, 0, 0);
            }
            #pragma unroll
            for (int nt = 0; nt < 8; ++nt)
                #pragma unroll
                for (int r = 0; r < 4; ++r)
                    s_ho[(rw + quad * 4 + r) * MSTR + nt * 16 + l16] = f2bf(ap[nt][r]);
            ushort* dst = pass ? Q : P;
            #pragma unroll
            for (int i = 0; i < 4; ++i) {
                int row = rw + i * 4 + quad;
                short8 v = *(const short8*)&s_ho[row * MSTR + l16 * 8];
                *(short8*)(dst + ((size_t)b * NP + n0 + row) * DD + l16 * 8) = v;
            }
        }
    }
}

#define NPC 50
__global__ void k_mean(const ushort* __restrict__ hb, float* __restrict__ hm) {
    int b  = blockIdx.y;
    int n0 = blockIdx.x * NPC;
    int d  = threadIdx.x;
    float s = 0.0f;
    for (int n = n0; n < n0 + NPC; ++n) s += bf2f(hb[((size_t)b * NP + n) * DD + d]);
    atomicAdd(&hm[b * DD + d], s);
}

__global__ void k_proj(const float* __restrict__ hm, const float* __restrict__ wp,
                       const float* __restrict__ bp, float* __restrict__ out) {
    int t = threadIdx.x;
    int b = t >> 6, o = t & (OUTD - 1);
    float s = 0.0f;
    for (int d2 = 0; d2 < DD; ++d2) s += hm[b * DD + d2] * wp[d2 * OUTD + o];
    s = s * (1.0f / NN) + bp[o];
    out[b * OUTD + o] = lrelu(s);
}

extern "C" void kernel_launch(void* const* d_in, const int* in_sizes, int n_in,
                              void* d_out, int out_size, void* d_ws, size_t ws_size,
                              hipStream_t stream) {
    (void)in_sizes; (void)n_in; (void)out_size; (void)ws_size;
    const float* x   = (const float*)d_in[0];
    const int*   ei  = (const int*)d_in[1];
    const float* w0  = (const float*)d_in[2];
    const float* b0  = (const float*)d_in[3];
    const float* ew1 = (const float*)d_in[4];
    const float* eb1 = (const float*)d_in[5];
    const float* ew2 = (const float*)d_in[6];
    const float* eb2 = (const float*)d_in[7];
    const float* cw  = (const float*)d_in[8];
    const float* cb  = (const float*)d_in[9];
    const float* nw1 = (const float*)d_in[10];
    const float* nb1 = (const float*)d_in[11];
    const float* nw2 = (const float*)d_in[12];
    const float* nb2 = (const float*)d_in[13];
    const float* wp  = (const float*)d_in[14];
    const float* bp  = (const float*)d_in[15];
    const int* row = ei;
    const int* col = ei + EE;

    const size_t HSZ = (size_t)BB * NP * DD;
    float* ws   = (float*)d_ws;
    float* aggr = ws;
    float* pos  = aggr + HSZ;
    float* cnt  = pos + (size_t)BB * NN * 3;
    float* hm   = cnt + NN;
    ushort* hb    = (ushort*)(hm + 512);
    ushort* Pb    = hb + HSZ;
    ushort* Qb    = Pb + HSZ;
    ushort* wtopf = Qb + HSZ;                           // LL*16384
    ushort* wmidf = wtopf + (size_t)LL * 16384;
    ushort* ew2f  = wmidf + (size_t)LL * 16384;
    ushort* nw1f  = ew2f + (size_t)LL * 16384;          // LL*32768
    ushort* nw2f  = nw1f + (size_t)LL * 32768;
    int* ecnt   = (int*)(nw2f + (size_t)LL * 16384);
    int* cursor = ecnt + NN;
    int* rowS   = cursor + NN;
    int* colS   = rowS + EE;

    hipMemcpyAsync(pos, x, sizeof(float) * (size_t)BB * NN * 3,
                   hipMemcpyDeviceToDevice, stream);
    hipMemsetAsync(cnt, 0, sizeof(float) * NN, stream);
    hipMemsetAsync(ecnt, 0, sizeof(int) * NN, stream);
    hipMemsetAsync(hm, 0, sizeof(float) * BB * DD, stream);
    hipMemsetAsync(aggr, 0, sizeof(float) * HSZ, stream);   // layers 1..3 self-cleaned by k_node

    k_cvtw_all<<<192, 256, 0, stream>>>(ew1, ew2, nw1, nw2,
                                        wtopf, wmidf, ew2f, nw1f, nw2f);

    k_h0<<<((int)HSZ + 255) / 256, 256, 0, stream>>>(x, w0, b0, hb);
    k_count<<<(EE + 255) / 256, 256, 0, stream>>>(col, cnt, ecnt);
    k_scan<<<1, 256, 0, stream>>>(ecnt, cursor);
    k_place<<<(EE + 255) / 256, 256, 0, stream>>>(row, col, cursor, rowS, colS);

    k_pq<<<(NP / 64) * BB, 256, 0, stream>>>(hb, wtopf, wmidf, eb1, Pb, Qb);

    for (int i = 0; i < LL; ++i) {
        k_edge<<<(EE / 128) * BB, 256, 0, stream>>>(
            pos, Pb, Qb, rowS, colS,
            ew1 + (size_t)i * 257 * DD + (size_t)256 * DD,
            ew2f + (size_t)i * 16384,
            eb2 + (size_t)i * DD,
            aggr);
        int nx = (i < LL - 1) ? (i + 1) : i;
        k_node<<<(NP / 64) * BB, 256, 0, stream>>>(
            hb, aggr, cnt,
            cw + (size_t)i * DD, cb + i,
            nw1f + (size_t)i * 32768, nb1 + (size_t)i * DD,
            nw2f + (size_t)i * 16384, nb2 + (size_t)i * DD,
            pos,
            (i < LL - 1) ? 1 : 0,
            wtopf + (size_t)nx * 16384, wmidf + (size_t)nx * 16384,
            eb1 + (size_t)nx * DD,
            Pb, Qb);
    }

    k_mean<<<dim3(NN / NPC, BB), DD, 0, stream>>>(hb, hm);
    k_proj<<<1, 256, 0, stream>>>(hm, wp, bp, (float*)d_out);
}